// Round 1
// baseline (577.608 us; speedup 1.0000x reference)
//
#include <hip/hip_runtime.h>
#include <math.h>

#define N 512
#define NN (N * N)
#define C 16
#define K 262144
#define LOG2N 9
#define NCOL 8

// ---------------- prep: per-point cell index + sign-folded dcf ----------------
__global__ __launch_bounds__(256) void prep_kernel(const float2* __restrict__ traj,
                                                   const float* __restrict__ dcf,
                                                   int* __restrict__ cell,
                                                   float* __restrict__ sdcf) {
    int k = blockIdx.x * 256 + threadIdx.x;
    float2 t = traj[k];
    // jnp.round is half-to-even; __float2int_rn matches.
    int iy = __float2int_rn((t.x + 0.5f) * (float)N) & (N - 1);
    int ix = __float2int_rn((t.y + 0.5f) * (float)N) & (N - 1);
    cell[k] = iy * N + ix;
    float s = ((iy + ix) & 1) ? -1.0f : 1.0f;   // ifftshift folded into input sign
    sdcf[k] = dcf[k] * s;
}

// ---------------- scatter: (c,k) -> grid[c][cell] atomic add ----------------
__global__ __launch_bounds__(256) void scatter_kernel(const float* __restrict__ xr,
                                                      const float* __restrict__ xi,
                                                      const int* __restrict__ cell,
                                                      const float* __restrict__ sdcf,
                                                      float* __restrict__ grid) {
    int idx = blockIdx.x * 256 + threadIdx.x;   // idx = c*K + k
    int k = idx & (K - 1);
    float v = sdcf[k];
    float vr = xr[idx] * v;
    float vi = xi[idx] * v;
    int c = idx >> 18;                           // K = 2^18
    float* p = grid + 2 * ((size_t)c * NN + cell[k]);
    atomicAdd(p, vr);
    atomicAdd(p + 1, vi);
}

// ---------------- row FFT: one 512-pt inverse-exponent FFT per block ----------------
__global__ __launch_bounds__(256) void rowfft_kernel(float2* __restrict__ grid) {
    __shared__ float sr[N];
    __shared__ float si[N];
    int blk = blockIdx.x;                        // c*512 + row
    float2* base = grid + (size_t)blk * N;
    int t = threadIdx.x;

    for (int i = t; i < N; i += 256) { float2 v = base[i]; sr[i] = v.x; si[i] = v.y; }
    __syncthreads();
    // bit-reversal permutation
    for (int i = t; i < N; i += 256) {
        int j = __brev((unsigned)i) >> (32 - LOG2N);
        if (j > i) {
            float a = sr[i]; sr[i] = sr[j]; sr[j] = a;
            float b = si[i]; si[i] = si[j]; si[j] = b;
        }
    }
    __syncthreads();
    // 9 radix-2 DIT stages, +i exponent (inverse DFT, unnormalized)
    for (int s = 1; s <= LOG2N; ++s) {
        int half = 1 << (s - 1);
        int m = half << 1;
        int j = t & (half - 1);
        int grp = t >> (s - 1);
        int p1 = grp * m + j;
        int p2 = p1 + half;
        float ang = 6.283185307179586f * (float)j / (float)m;
        float sn, cs;
        __sincosf(ang, &sn, &cs);
        float xr2 = sr[p2], xi2 = si[p2];
        float tr = cs * xr2 - sn * xi2;
        float ti = cs * xi2 + sn * xr2;
        float ur = sr[p1], ui = si[p1];
        sr[p2] = ur - tr; si[p2] = ui - ti;
        sr[p1] = ur + tr; si[p1] = ui + ti;
        __syncthreads();
    }
    for (int i = t; i < N; i += 256) { base[i] = make_float2(sr[i], si[i]); }
}

// ---------------- column FFT: NCOL columns per block through LDS ----------------
__global__ __launch_bounds__(256) void colfft_kernel(float2* __restrict__ grid) {
    __shared__ float sr[N * NCOL];
    __shared__ float si[N * NCOL];
    int blk = blockIdx.x;                        // c * (N/NCOL) + cg
    int c = blk >> 6;                            // N/NCOL = 64
    int cg = blk & 63;
    float2* base = grid + (size_t)c * NN + cg * NCOL;
    int t = threadIdx.x;

    for (int e = t; e < N * NCOL; e += 256) {
        int row = e >> 3, col = e & 7;
        float2 v = base[(size_t)row * N + col];
        sr[e] = v.x; si[e] = v.y;
    }
    __syncthreads();

    int col = t & 7;
    int tg = t >> 3;                             // 0..31 threads per column
    for (int i = tg; i < N; i += 32) {
        int j = __brev((unsigned)i) >> (32 - LOG2N);
        if (j > i) {
            int a1 = i * NCOL + col, a2 = j * NCOL + col;
            float a = sr[a1]; sr[a1] = sr[a2]; sr[a2] = a;
            float b = si[a1]; si[a1] = si[a2]; si[a2] = b;
        }
    }
    __syncthreads();

    for (int s = 1; s <= LOG2N; ++s) {
        int half = 1 << (s - 1);
        int m = half << 1;
        for (int b = tg; b < 256; b += 32) {
            int j = b & (half - 1);
            int grp = b >> (s - 1);
            int p1 = grp * m + j;
            int p2 = p1 + half;
            float ang = 6.283185307179586f * (float)j / (float)m;
            float sn, cs;
            __sincosf(ang, &sn, &cs);
            int a1 = p1 * NCOL + col, a2 = p2 * NCOL + col;
            float xr2 = sr[a2], xi2 = si[a2];
            float tr = cs * xr2 - sn * xi2;
            float ti = cs * xi2 + sn * xr2;
            float ur = sr[a1], ui = si[a1];
            sr[a2] = ur - tr; si[a2] = ui - ti;
            sr[a1] = ur + tr; si[a1] = ui + ti;
        }
        __syncthreads();
    }

    for (int e = t; e < N * NCOL; e += 256) {
        int row = e >> 3, col2 = e & 7;
        base[(size_t)row * N + col2] = make_float2(sr[e], si[e]);
    }
}

// ---------------- combine: out = (-1)^(ny+nx) * sum_c conj(csm)*img ----------------
__global__ __launch_bounds__(256) void combine_kernel(const float* __restrict__ csr,
                                                      const float* __restrict__ csi,
                                                      const float2* __restrict__ grid,
                                                      float* __restrict__ out) {
    int pix = blockIdx.x * 256 + threadIdx.x;    // 0..NN-1
    int ny = pix >> LOG2N, nx = pix & (N - 1);
    float ar = 0.f, ai = 0.f;
#pragma unroll
    for (int c = 0; c < C; ++c) {
        float2 uv = grid[(size_t)c * NN + pix];
        float a = csr[c * NN + pix];
        float b = csi[c * NN + pix];
        // conj(csm)*img = (a - i b)(u + i v) = (a u + b v) + i (a v - b u)
        ar += a * uv.x + b * uv.y;
        ai += a * uv.y - b * uv.x;
    }
    float s = ((ny + nx) & 1) ? -1.f : 1.f;      // fftshift folded into output sign
    out[pix] = s * ar;
    out[NN + pix] = s * ai;
}

extern "C" void kernel_launch(void* const* d_in, const int* in_sizes, int n_in,
                              void* d_out, int out_size, void* d_ws, size_t ws_size,
                              hipStream_t stream) {
    const float* x_real   = (const float*)d_in[0];
    const float* x_imag   = (const float*)d_in[1];
    const float* csm_real = (const float*)d_in[2];
    const float* csm_imag = (const float*)d_in[3];
    const float2* traj    = (const float2*)d_in[4];
    const float* dcf      = (const float*)d_in[5];
    float* out = (float*)d_out;

    char* ws = (char*)d_ws;
    float* grid = (float*)ws;                                   // C*NN*2 floats = 32 MB
    int*   cell = (int*)(ws + (size_t)C * NN * 2 * sizeof(float));
    float* sdcf = (float*)(ws + (size_t)C * NN * 2 * sizeof(float) + (size_t)K * sizeof(int));

    hipMemsetAsync(grid, 0, (size_t)C * NN * 2 * sizeof(float), stream);

    prep_kernel<<<K / 256, 256, 0, stream>>>(traj, dcf, cell, sdcf);
    scatter_kernel<<<(C * K) / 256, 256, 0, stream>>>(x_real, x_imag, cell, sdcf, grid);
    rowfft_kernel<<<C * N, 256, 0, stream>>>((float2*)grid);
    colfft_kernel<<<C * (N / NCOL), 256, 0, stream>>>((float2*)grid);
    combine_kernel<<<NN / 256, 256, 0, stream>>>(csm_real, csm_imag, (float2*)grid, out);
}

// Round 2
// 577.270 us; speedup vs baseline: 1.0006x; 1.0006x over previous
//
#include <hip/hip_runtime.h>
#include <math.h>

#define N 512
#define NN (N * N)
#define C 16
#define K 262144
#define LOG2N 9
#define NCOL 8

// ---------------- prep: per-point cell index + sign-folded dcf ----------------
__global__ __launch_bounds__(256) void prep_kernel(const float2* __restrict__ traj,
                                                   const float* __restrict__ dcf,
                                                   int* __restrict__ cell,
                                                   float* __restrict__ sdcf) {
    int k = blockIdx.x * 256 + threadIdx.x;
    float2 t = traj[k];
    // jnp.round is half-to-even; __float2int_rn matches.
    int iy = __float2int_rn((t.x + 0.5f) * (float)N) & (N - 1);
    int ix = __float2int_rn((t.y + 0.5f) * (float)N) & (N - 1);
    cell[k] = iy * N + ix;
    float s = ((iy + ix) & 1) ? -1.0f : 1.0f;   // ifftshift folded into input sign
    sdcf[k] = dcf[k] * s;
}

// ---------------- scatter: XCD-blocked by channel ----------------
// blockIdx = chunk*16 + c  ->  XCD = blockIdx % 8 = c % 8 (round-robin dispatch),
// so each XCD's 4 MB L2 holds exactly its two channels' 2 MB grids; atomic RMW
// lines stay L2-resident until fully accumulated instead of thrashing to HBM.
// 2048 blocks x 4 waves = 8 blocks/CU -> fully co-resident, mapping stable.
#define PTS_PER_BLK 2048
__global__ __launch_bounds__(256) void scatter_kernel(const float* __restrict__ xr,
                                                      const float* __restrict__ xi,
                                                      const int* __restrict__ cell,
                                                      const float* __restrict__ sdcf,
                                                      float* __restrict__ grid) {
    int b = blockIdx.x;
    int c = b & 15;
    int k0 = (b >> 4) * PTS_PER_BLK;
    const float* xrc = xr + (size_t)c * K;
    const float* xic = xi + (size_t)c * K;
    float* g = grid + (size_t)c * NN * 2;
    for (int i = threadIdx.x; i < PTS_PER_BLK; i += 256) {
        int k = k0 + i;
        float v = sdcf[k];
        float vr = __builtin_nontemporal_load(&xrc[k]) * v;  // don't pollute L2
        float vi = __builtin_nontemporal_load(&xic[k]) * v;
        int cl = cell[k];
        atomicAdd(&g[2 * cl], vr);
        atomicAdd(&g[2 * cl + 1], vi);
    }
}

// ---------------- row FFT: one 512-pt inverse-exponent FFT per block ----------------
__global__ __launch_bounds__(256) void rowfft_kernel(float2* __restrict__ grid) {
    __shared__ float sr[N];
    __shared__ float si[N];
    int blk = blockIdx.x;                        // c*512 + row
    float2* base = grid + (size_t)blk * N;
    int t = threadIdx.x;

    for (int i = t; i < N; i += 256) { float2 v = base[i]; sr[i] = v.x; si[i] = v.y; }
    __syncthreads();
    // bit-reversal permutation
    for (int i = t; i < N; i += 256) {
        int j = __brev((unsigned)i) >> (32 - LOG2N);
        if (j > i) {
            float a = sr[i]; sr[i] = sr[j]; sr[j] = a;
            float b = si[i]; si[i] = si[j]; si[j] = b;
        }
    }
    __syncthreads();
    // 9 radix-2 DIT stages, +i exponent (inverse DFT, unnormalized)
    for (int s = 1; s <= LOG2N; ++s) {
        int half = 1 << (s - 1);
        int m = half << 1;
        int j = t & (half - 1);
        int grp = t >> (s - 1);
        int p1 = grp * m + j;
        int p2 = p1 + half;
        float ang = 6.283185307179586f * (float)j / (float)m;
        float sn, cs;
        __sincosf(ang, &sn, &cs);
        float xr2 = sr[p2], xi2 = si[p2];
        float tr = cs * xr2 - sn * xi2;
        float ti = cs * xi2 + sn * xr2;
        float ur = sr[p1], ui = si[p1];
        sr[p2] = ur - tr; si[p2] = ui - ti;
        sr[p1] = ur + tr; si[p1] = ui + ti;
        __syncthreads();
    }
    for (int i = t; i < N; i += 256) { base[i] = make_float2(sr[i], si[i]); }
}

// ---------------- column FFT: NCOL columns per block through LDS ----------------
__global__ __launch_bounds__(256) void colfft_kernel(float2* __restrict__ grid) {
    __shared__ float sr[N * NCOL];
    __shared__ float si[N * NCOL];
    int blk = blockIdx.x;                        // c * (N/NCOL) + cg
    int c = blk >> 6;                            // N/NCOL = 64
    int cg = blk & 63;
    float2* base = grid + (size_t)c * NN + cg * NCOL;
    int t = threadIdx.x;

    for (int e = t; e < N * NCOL; e += 256) {
        int row = e >> 3, col = e & 7;
        float2 v = base[(size_t)row * N + col];
        sr[e] = v.x; si[e] = v.y;
    }
    __syncthreads();

    int col = t & 7;
    int tg = t >> 3;                             // 0..31 threads per column
    for (int i = tg; i < N; i += 32) {
        int j = __brev((unsigned)i) >> (32 - LOG2N);
        if (j > i) {
            int a1 = i * NCOL + col, a2 = j * NCOL + col;
            float a = sr[a1]; sr[a1] = sr[a2]; sr[a2] = a;
            float b = si[a1]; si[a1] = si[a2]; si[a2] = b;
        }
    }
    __syncthreads();

    for (int s = 1; s <= LOG2N; ++s) {
        int half = 1 << (s - 1);
        int m = half << 1;
        for (int b = tg; b < 256; b += 32) {
            int j = b & (half - 1);
            int grp = b >> (s - 1);
            int p1 = grp * m + j;
            int p2 = p1 + half;
            float ang = 6.283185307179586f * (float)j / (float)m;
            float sn, cs;
            __sincosf(ang, &sn, &cs);
            int a1 = p1 * NCOL + col, a2 = p2 * NCOL + col;
            float xr2 = sr[a2], xi2 = si[a2];
            float tr = cs * xr2 - sn * xi2;
            float ti = cs * xi2 + sn * xr2;
            float ur = sr[a1], ui = si[a1];
            sr[a2] = ur - tr; si[a2] = ui - ti;
            sr[a1] = ur + tr; si[a1] = ui + ti;
        }
        __syncthreads();
    }

    for (int e = t; e < N * NCOL; e += 256) {
        int row = e >> 3, col2 = e & 7;
        base[(size_t)row * N + col2] = make_float2(sr[e], si[e]);
    }
}

// ---------------- combine: out = (-1)^(ny+nx) * sum_c conj(csm)*img ----------------
__global__ __launch_bounds__(256) void combine_kernel(const float* __restrict__ csr,
                                                      const float* __restrict__ csi,
                                                      const float2* __restrict__ grid,
                                                      float* __restrict__ out) {
    int pix = blockIdx.x * 256 + threadIdx.x;    // 0..NN-1
    int ny = pix >> LOG2N, nx = pix & (N - 1);
    float ar = 0.f, ai = 0.f;
#pragma unroll
    for (int c = 0; c < C; ++c) {
        float2 uv = grid[(size_t)c * NN + pix];
        float a = csr[c * NN + pix];
        float b = csi[c * NN + pix];
        // conj(csm)*img = (a - i b)(u + i v) = (a u + b v) + i (a v - b u)
        ar += a * uv.x + b * uv.y;
        ai += a * uv.y - b * uv.x;
    }
    float s = ((ny + nx) & 1) ? -1.f : 1.f;      // fftshift folded into output sign
    out[pix] = s * ar;
    out[NN + pix] = s * ai;
}

extern "C" void kernel_launch(void* const* d_in, const int* in_sizes, int n_in,
                              void* d_out, int out_size, void* d_ws, size_t ws_size,
                              hipStream_t stream) {
    const float* x_real   = (const float*)d_in[0];
    const float* x_imag   = (const float*)d_in[1];
    const float* csm_real = (const float*)d_in[2];
    const float* csm_imag = (const float*)d_in[3];
    const float2* traj    = (const float2*)d_in[4];
    const float* dcf      = (const float*)d_in[5];
    float* out = (float*)d_out;

    char* ws = (char*)d_ws;
    float* grid = (float*)ws;                                   // C*NN*2 floats = 32 MB
    int*   cell = (int*)(ws + (size_t)C * NN * 2 * sizeof(float));
    float* sdcf = (float*)(ws + (size_t)C * NN * 2 * sizeof(float) + (size_t)K * sizeof(int));

    hipMemsetAsync(grid, 0, (size_t)C * NN * 2 * sizeof(float), stream);

    prep_kernel<<<K / 256, 256, 0, stream>>>(traj, dcf, cell, sdcf);
    scatter_kernel<<<(C * K) / PTS_PER_BLK, 256, 0, stream>>>(x_real, x_imag, cell, sdcf, grid);
    rowfft_kernel<<<C * N, 256, 0, stream>>>((float2*)grid);
    colfft_kernel<<<C * (N / NCOL), 256, 0, stream>>>((float2*)grid);
    combine_kernel<<<NN / 256, 256, 0, stream>>>(csm_real, csm_imag, (float2*)grid, out);
}

// Round 4
// 265.232 us; speedup vs baseline: 2.1777x; 2.1765x over previous
//
#include <hip/hip_runtime.h>
#include <math.h>

#define N 512
#define NN (N * N)
#define C 16
#define K 262144
#define LOG2N 9
#define NCOL 8

// ============ phase 1: bin points by cell (counting sort, no fp atomics) ============

// prep + histogram fused: cell index, sign-folded dcf, count per cell
__global__ __launch_bounds__(256) void prep_hist_kernel(const float2* __restrict__ traj,
                                                        const float* __restrict__ dcf,
                                                        int* __restrict__ cell,
                                                        float* __restrict__ sdcf,
                                                        int* __restrict__ count) {
    int k = blockIdx.x * 256 + threadIdx.x;
    float2 t = traj[k];
    // jnp.round is half-to-even; __float2int_rn matches.
    int iy = __float2int_rn((t.x + 0.5f) * (float)N) & (N - 1);
    int ix = __float2int_rn((t.y + 0.5f) * (float)N) & (N - 1);
    int cl = iy * N + ix;
    cell[k] = cl;
    float s = ((iy + ix) & 1) ? -1.0f : 1.0f;   // ifftshift folded into input sign
    sdcf[k] = dcf[k] * s;
    atomicAdd(&count[cl], 1);                    // avg 1 pt/cell -> low contention
}

// per-block reduce: 256 blocks x 1024 ints -> bsum[256]
__global__ __launch_bounds__(256) void scan_reduce_kernel(const int* __restrict__ count,
                                                          int* __restrict__ bsum) {
    __shared__ int sd[256];
    int t = threadIdx.x;
    const int4* c4 = (const int4*)count;
    int4 v = c4[blockIdx.x * 256 + t];
    sd[t] = v.x + v.y + v.z + v.w;
    __syncthreads();
    for (int d = 128; d > 0; d >>= 1) {
        if (t < d) sd[t] += sd[t + d];
        __syncthreads();
    }
    if (t == 0) bsum[blockIdx.x] = sd[0];
}

// single block: exclusive scan of bsum[256] -> boffs[256]; also offs[NN] = K
__global__ __launch_bounds__(256) void scan_top_kernel(const int* __restrict__ bsum,
                                                       int* __restrict__ boffs,
                                                       int* __restrict__ offs) {
    __shared__ int sd[256];
    int t = threadIdx.x;
    int v = bsum[t];
    sd[t] = v;
    __syncthreads();
    for (int d = 1; d < 256; d <<= 1) {
        int tmp = (t >= d) ? sd[t - d] : 0;
        __syncthreads();
        sd[t] += tmp;
        __syncthreads();
    }
    boffs[t] = sd[t] - v;   // exclusive
    if (t == 0) offs[NN] = K;
}

// per-block exclusive scan: offs[i] = global exclusive prefix; cursor = copy of offs
__global__ __launch_bounds__(256) void scan_final_kernel(const int* __restrict__ count,
                                                         const int* __restrict__ boffs,
                                                         int* __restrict__ offs,
                                                         int* __restrict__ cursor) {
    __shared__ int sd[256];
    int t = threadIdx.x;
    int base_idx = blockIdx.x * 256 + t;
    const int4* c4 = (const int4*)count;
    int4 v = c4[base_idx];
    int s = v.x + v.y + v.z + v.w;
    sd[t] = s;
    __syncthreads();
    for (int d = 1; d < 256; d <<= 1) {
        int tmp = (t >= d) ? sd[t - d] : 0;
        __syncthreads();
        sd[t] += tmp;
        __syncthreads();
    }
    int base = boffs[blockIdx.x] + sd[t] - s;    // global exclusive prefix for this thread's 4
    int4 o;
    o.x = base;
    o.y = base + v.x;
    o.z = base + v.x + v.y;
    o.w = base + v.x + v.y + v.z;
    ((int4*)offs)[base_idx] = o;
    ((int4*)cursor)[base_idx] = o;
}

// place: each point claims a unique slot in its cell's range
__global__ __launch_bounds__(256) void place_kernel(const int* __restrict__ cell,
                                                    const float* __restrict__ sdcf,
                                                    int* __restrict__ cursor,
                                                    int* __restrict__ perm,
                                                    float* __restrict__ svals) {
    int k = blockIdx.x * 256 + threadIdx.x;
    int cl = cell[k];
    int p = atomicAdd(&cursor[cl], 1);
    perm[p] = k;
    svals[p] = sdcf[k];
}

// grid build: gather — one thread per (channel, cell); x gathers hit L2 (2 MB/channel)
#define CELLS_PER_BLK 2048
__global__ __launch_bounds__(256) void grid_build_kernel(const int* __restrict__ offs,
                                                         const int* __restrict__ perm,
                                                         const float* __restrict__ svals,
                                                         const float* __restrict__ xr,
                                                         const float* __restrict__ xi,
                                                         float2* __restrict__ grid) {
    int b = blockIdx.x;                  // 2048 blocks: c = b&15 spreads channels over XCDs
    int c = b & 15;
    int cell0 = (b >> 4) * CELLS_PER_BLK;
    const float* xrc = xr + (size_t)c * K;
    const float* xic = xi + (size_t)c * K;
    float2* g = grid + (size_t)c * NN;
    for (int i = threadIdx.x; i < CELLS_PER_BLK; i += 256) {
        int cl = cell0 + i;
        int s = offs[cl], e = offs[cl + 1];
        float ar = 0.f, ai = 0.f;
        for (int p = s; p < e; ++p) {
            int k = perm[p];
            float w = svals[p];
            ar += xrc[k] * w;
            ai += xic[k] * w;
        }
        g[cl] = make_float2(ar, ai);     // empty cells write 0 -> no grid memset needed
    }
}

// ============ phase 2: FFT + combine (unchanged this round) ============

__global__ __launch_bounds__(256) void rowfft_kernel(float2* __restrict__ grid) {
    __shared__ float sr[N];
    __shared__ float si[N];
    int blk = blockIdx.x;                        // c*512 + row
    float2* base = grid + (size_t)blk * N;
    int t = threadIdx.x;

    for (int i = t; i < N; i += 256) { float2 v = base[i]; sr[i] = v.x; si[i] = v.y; }
    __syncthreads();
    for (int i = t; i < N; i += 256) {
        int j = __brev((unsigned)i) >> (32 - LOG2N);
        if (j > i) {
            float a = sr[i]; sr[i] = sr[j]; sr[j] = a;
            float b = si[i]; si[i] = si[j]; si[j] = b;
        }
    }
    __syncthreads();
    for (int s = 1; s <= LOG2N; ++s) {
        int half = 1 << (s - 1);
        int m = half << 1;
        int j = t & (half - 1);
        int grp = t >> (s - 1);
        int p1 = grp * m + j;
        int p2 = p1 + half;
        float ang = 6.283185307179586f * (float)j / (float)m;
        float sn, cs;
        __sincosf(ang, &sn, &cs);
        float xr2 = sr[p2], xi2 = si[p2];
        float tr = cs * xr2 - sn * xi2;
        float ti = cs * xi2 + sn * xr2;
        float ur = sr[p1], ui = si[p1];
        sr[p2] = ur - tr; si[p2] = ui - ti;
        sr[p1] = ur + tr; si[p1] = ui + ti;
        __syncthreads();
    }
    for (int i = t; i < N; i += 256) { base[i] = make_float2(sr[i], si[i]); }
}

__global__ __launch_bounds__(256) void colfft_kernel(float2* __restrict__ grid) {
    __shared__ float sr[N * NCOL];
    __shared__ float si[N * NCOL];
    int blk = blockIdx.x;                        // c * (N/NCOL) + cg
    int c = blk >> 6;
    int cg = blk & 63;
    float2* base = grid + (size_t)c * NN + cg * NCOL;
    int t = threadIdx.x;

    for (int e = t; e < N * NCOL; e += 256) {
        int row = e >> 3, col = e & 7;
        float2 v = base[(size_t)row * N + col];
        sr[e] = v.x; si[e] = v.y;
    }
    __syncthreads();

    int col = t & 7;
    int tg = t >> 3;
    for (int i = tg; i < N; i += 32) {
        int j = __brev((unsigned)i) >> (32 - LOG2N);
        if (j > i) {
            int a1 = i * NCOL + col, a2 = j * NCOL + col;
            float a = sr[a1]; sr[a1] = sr[a2]; sr[a2] = a;
            float b = si[a1]; si[a1] = si[a2]; si[a2] = b;
        }
    }
    __syncthreads();

    for (int s = 1; s <= LOG2N; ++s) {
        int half = 1 << (s - 1);
        int m = half << 1;
        for (int b = tg; b < 256; b += 32) {
            int j = b & (half - 1);
            int grp = b >> (s - 1);
            int p1 = grp * m + j;
            int p2 = p1 + half;
            float ang = 6.283185307179586f * (float)j / (float)m;
            float sn, cs;
            __sincosf(ang, &sn, &cs);
            int a1 = p1 * NCOL + col, a2 = p2 * NCOL + col;
            float xr2 = sr[a2], xi2 = si[a2];
            float tr = cs * xr2 - sn * xi2;
            float ti = cs * xi2 + sn * xr2;
            float ur = sr[a1], ui = si[a1];
            sr[a2] = ur - tr; si[a2] = ui - ti;
            sr[a1] = ur + tr; si[a1] = ui + ti;
        }
        __syncthreads();
    }

    for (int e = t; e < N * NCOL; e += 256) {
        int row = e >> 3, col2 = e & 7;
        base[(size_t)row * N + col2] = make_float2(sr[e], si[e]);
    }
}

__global__ __launch_bounds__(256) void combine_kernel(const float* __restrict__ csr,
                                                      const float* __restrict__ csi,
                                                      const float2* __restrict__ grid,
                                                      float* __restrict__ out) {
    int pix = blockIdx.x * 256 + threadIdx.x;
    int ny = pix >> LOG2N, nx = pix & (N - 1);
    float ar = 0.f, ai = 0.f;
#pragma unroll
    for (int c = 0; c < C; ++c) {
        float2 uv = grid[(size_t)c * NN + pix];
        float a = csr[c * NN + pix];
        float b = csi[c * NN + pix];
        ar += a * uv.x + b * uv.y;
        ai += a * uv.y - b * uv.x;
    }
    float s = ((ny + nx) & 1) ? -1.f : 1.f;      // fftshift folded into output sign
    out[pix] = s * ar;
    out[NN + pix] = s * ai;
}

extern "C" void kernel_launch(void* const* d_in, const int* in_sizes, int n_in,
                              void* d_out, int out_size, void* d_ws, size_t ws_size,
                              hipStream_t stream) {
    const float* x_real   = (const float*)d_in[0];
    const float* x_imag   = (const float*)d_in[1];
    const float* csm_real = (const float*)d_in[2];
    const float* csm_imag = (const float*)d_in[3];
    const float2* traj    = (const float2*)d_in[4];
    const float* dcf      = (const float*)d_in[5];
    float* out = (float*)d_out;

    char* ws = (char*)d_ws;
    size_t o = 0;
    float* grid  = (float*)(ws + o); o += (size_t)C * NN * 2 * sizeof(float);  // 32 MB
    int*   cell  = (int*)(ws + o);   o += (size_t)K * sizeof(int);             // 1 MB
    float* sdcf  = (float*)(ws + o); o += (size_t)K * sizeof(float);           // 1 MB
    int*   count = (int*)(ws + o);   o += (size_t)NN * sizeof(int);            // 1 MB
    int*   offs  = (int*)(ws + o);   o += ((size_t)NN + 4) * sizeof(int);      // 1 MB (+pad, 16B-aligned)
    int*   cursor= (int*)(ws + o);   o += (size_t)NN * sizeof(int);            // 1 MB
    int*   perm  = (int*)(ws + o);   o += (size_t)K * sizeof(int);             // 1 MB
    float* svals = (float*)(ws + o); o += (size_t)K * sizeof(float);           // 1 MB
    int*   bsum  = (int*)(ws + o);   o += 256 * sizeof(int);
    int*   boffs = (int*)(ws + o);   o += 256 * sizeof(int);

    (void)hipMemsetAsync(count, 0, (size_t)NN * sizeof(int), stream);

    prep_hist_kernel<<<K / 256, 256, 0, stream>>>(traj, dcf, cell, sdcf, count);
    scan_reduce_kernel<<<256, 256, 0, stream>>>(count, bsum);
    scan_top_kernel<<<1, 256, 0, stream>>>(bsum, boffs, offs);
    scan_final_kernel<<<256, 256, 0, stream>>>(count, boffs, offs, cursor);
    place_kernel<<<K / 256, 256, 0, stream>>>(cell, sdcf, cursor, perm, svals);
    grid_build_kernel<<<(C * NN) / CELLS_PER_BLK, 256, 0, stream>>>(offs, perm, svals,
                                                                    x_real, x_imag, (float2*)grid);
    rowfft_kernel<<<C * N, 256, 0, stream>>>((float2*)grid);
    colfft_kernel<<<C * (N / NCOL), 256, 0, stream>>>((float2*)grid);
    combine_kernel<<<NN / 256, 256, 0, stream>>>(csm_real, csm_imag, (float2*)grid, out);
}

// Round 6
// 250.774 us; speedup vs baseline: 2.3033x; 1.0577x over previous
//
#include <hip/hip_runtime.h>
#include <math.h>

#define N 512
#define NN (N * N)
#define C 16
#define K 262144
#define LOG2N 9
#define NCOL 8

// ============ phase 1: bin points by cell (counting sort, no fp atomics) ============

// prep + histogram fused: cell index, sign-folded dcf, count per cell
__global__ __launch_bounds__(256) void prep_hist_kernel(const float2* __restrict__ traj,
                                                        const float* __restrict__ dcf,
                                                        int* __restrict__ cell,
                                                        float* __restrict__ sdcf,
                                                        int* __restrict__ count) {
    int k = blockIdx.x * 256 + threadIdx.x;
    float2 t = traj[k];
    // jnp.round is half-to-even; __float2int_rn matches.
    int iy = __float2int_rn((t.x + 0.5f) * (float)N) & (N - 1);
    int ix = __float2int_rn((t.y + 0.5f) * (float)N) & (N - 1);
    int cl = iy * N + ix;
    cell[k] = cl;
    float s = ((iy + ix) & 1) ? -1.0f : 1.0f;   // ifftshift folded into input sign
    sdcf[k] = dcf[k] * s;
    atomicAdd(&count[cl], 1);                    // avg 1 pt/cell -> low contention
}

// per-block reduce: 256 blocks x 1024 ints -> bsum[256]
__global__ __launch_bounds__(256) void scan_reduce_kernel(const int* __restrict__ count,
                                                          int* __restrict__ bsum) {
    __shared__ int sd[256];
    int t = threadIdx.x;
    const int4* c4 = (const int4*)count;
    int4 v = c4[blockIdx.x * 256 + t];
    sd[t] = v.x + v.y + v.z + v.w;
    __syncthreads();
    for (int d = 128; d > 0; d >>= 1) {
        if (t < d) sd[t] += sd[t + d];
        __syncthreads();
    }
    if (t == 0) bsum[blockIdx.x] = sd[0];
}

// single block: exclusive scan of bsum[256] -> boffs[256]; also offs[NN] = K
__global__ __launch_bounds__(256) void scan_top_kernel(const int* __restrict__ bsum,
                                                       int* __restrict__ boffs,
                                                       int* __restrict__ offs) {
    __shared__ int sd[256];
    int t = threadIdx.x;
    int v = bsum[t];
    sd[t] = v;
    __syncthreads();
    for (int d = 1; d < 256; d <<= 1) {
        int tmp = (t >= d) ? sd[t - d] : 0;
        __syncthreads();
        sd[t] += tmp;
        __syncthreads();
    }
    boffs[t] = sd[t] - v;   // exclusive
    if (t == 0) offs[NN] = K;
}

// per-block exclusive scan: offs[i] = global exclusive prefix; cursor = copy of offs
__global__ __launch_bounds__(256) void scan_final_kernel(const int* __restrict__ count,
                                                         const int* __restrict__ boffs,
                                                         int* __restrict__ offs,
                                                         int* __restrict__ cursor) {
    __shared__ int sd[256];
    int t = threadIdx.x;
    int base_idx = blockIdx.x * 256 + t;
    const int4* c4 = (const int4*)count;
    int4 v = c4[base_idx];
    int s = v.x + v.y + v.z + v.w;
    sd[t] = s;
    __syncthreads();
    for (int d = 1; d < 256; d <<= 1) {
        int tmp = (t >= d) ? sd[t - d] : 0;
        __syncthreads();
        sd[t] += tmp;
        __syncthreads();
    }
    int base = boffs[blockIdx.x] + sd[t] - s;    // global exclusive prefix for this thread's 4
    int4 o;
    o.x = base;
    o.y = base + v.x;
    o.z = base + v.x + v.y;
    o.w = base + v.x + v.y + v.z;
    ((int4*)offs)[base_idx] = o;
    ((int4*)cursor)[base_idx] = o;
}

// place: each point claims a unique slot; pack {k, weight} into one 8B store
__global__ __launch_bounds__(256) void place_kernel(const int* __restrict__ cell,
                                                    const float* __restrict__ sdcf,
                                                    int* __restrict__ cursor,
                                                    long long* __restrict__ pw) {
    int k = blockIdx.x * 256 + threadIdx.x;
    int cl = cell[k];
    float w = sdcf[k];
    int p = atomicAdd(&cursor[cl], 1);
    unsigned long long packed = (unsigned int)k |
                                ((unsigned long long)(unsigned int)__float_as_int(w) << 32);
    pw[p] = (long long)packed;
}

// ============ fused grid-build + row FFT ============
// block = (row r, channel-group cg). blockIdx = r*8+cg -> XCD = cg (round-robin),
// so each XCD's L2 holds exactly its 2 channels' x arrays (4 MB). Metadata (pw,
// offs) is streamed with nontemporal loads so it doesn't evict x.
// Gathers both channels per point (4 parallel streams -> MLP), FFTs both rows
// in LDS, writes grid rows directly (no intermediate grid round-trip).
__global__ __launch_bounds__(256) void build_rowfft_kernel(const int* __restrict__ offs,
                                                           const long long* __restrict__ pw,
                                                           const float* __restrict__ xr,
                                                           const float* __restrict__ xi,
                                                           float2* __restrict__ grid) {
    __shared__ float sr0[N], si0[N], sr1[N], si1[N];
    __shared__ int soffs[N + 1];
    int b = blockIdx.x;
    int cg = b & 7;
    int r = b >> 3;
    int c0 = cg * 2;
    int t = threadIdx.x;
    const float* xr0 = xr + (size_t)c0 * K;
    const float* xi0 = xi + (size_t)c0 * K;
    const float* xr1 = xr + (size_t)(c0 + 1) * K;
    const float* xi1 = xi + (size_t)(c0 + 1) * K;

    for (int i = t; i < N + 1; i += 256) soffs[i] = offs[r * N + i];
    __syncthreads();

    // gather phase: 2 cells/thread, 4 gather streams per point
    for (int i = t; i < N; i += 256) {
        int s = soffs[i], e = soffs[i + 1];
        float a0 = 0.f, b0 = 0.f, a1 = 0.f, b1 = 0.f;
        for (int p = s; p < e; ++p) {
            unsigned long long kw = (unsigned long long)__builtin_nontemporal_load(&pw[p]);
            int k = (int)(unsigned int)kw;
            float w = __int_as_float((int)(kw >> 32));
            a0 += xr0[k] * w;
            b0 += xi0[k] * w;
            a1 += xr1[k] * w;
            b1 += xi1[k] * w;
        }
        sr0[i] = a0; si0[i] = b0; sr1[i] = a1; si1[i] = b1;
    }
    __syncthreads();

    // bit-reversal permutation (both channels)
    for (int i = t; i < N; i += 256) {
        int j = __brev((unsigned)i) >> (32 - LOG2N);
        if (j > i) {
            float tmp;
            tmp = sr0[i]; sr0[i] = sr0[j]; sr0[j] = tmp;
            tmp = si0[i]; si0[i] = si0[j]; si0[j] = tmp;
            tmp = sr1[i]; sr1[i] = sr1[j]; sr1[j] = tmp;
            tmp = si1[i]; si1[i] = si1[j]; si1[j] = tmp;
        }
    }
    __syncthreads();

    // 9 radix-2 DIT stages, +i exponent; thread t = butterfly t of both channels
    for (int s = 1; s <= LOG2N; ++s) {
        int half = 1 << (s - 1);
        int m = half << 1;
        int j = t & (half - 1);
        int grp = t >> (s - 1);
        int p1 = grp * m + j;
        int p2 = p1 + half;
        float ang = 6.283185307179586f * (float)j / (float)m;
        float sn, cs;
        __sincosf(ang, &sn, &cs);
        float x2, y2, tr, ti, ur, ui;
        x2 = sr0[p2]; y2 = si0[p2];
        tr = cs * x2 - sn * y2; ti = cs * y2 + sn * x2;
        ur = sr0[p1]; ui = si0[p1];
        sr0[p2] = ur - tr; si0[p2] = ui - ti;
        sr0[p1] = ur + tr; si0[p1] = ui + ti;
        x2 = sr1[p2]; y2 = si1[p2];
        tr = cs * x2 - sn * y2; ti = cs * y2 + sn * x2;
        ur = sr1[p1]; ui = si1[p1];
        sr1[p2] = ur - tr; si1[p2] = ui - ti;
        sr1[p1] = ur + tr; si1[p1] = ui + ti;
        __syncthreads();
    }

    float2* g0 = grid + (size_t)c0 * NN + (size_t)r * N;
    float2* g1 = grid + (size_t)(c0 + 1) * NN + (size_t)r * N;
    for (int i = t; i < N; i += 256) {
        g0[i] = make_float2(sr0[i], si0[i]);
        g1[i] = make_float2(sr1[i], si1[i]);
    }
}

// ============ column FFT: NCOL columns per block through LDS ============
__global__ __launch_bounds__(256) void colfft_kernel(float2* __restrict__ grid) {
    __shared__ float sr[N * NCOL];
    __shared__ float si[N * NCOL];
    int blk = blockIdx.x;                        // c * (N/NCOL) + cg
    int c = blk >> 6;
    int cg = blk & 63;
    float2* base = grid + (size_t)c * NN + cg * NCOL;
    int t = threadIdx.x;

    for (int e = t; e < N * NCOL; e += 256) {
        int row = e >> 3, col = e & 7;
        float2 v = base[(size_t)row * N + col];
        sr[e] = v.x; si[e] = v.y;
    }
    __syncthreads();

    int col = t & 7;
    int tg = t >> 3;
    for (int i = tg; i < N; i += 32) {
        int j = __brev((unsigned)i) >> (32 - LOG2N);
        if (j > i) {
            int a1 = i * NCOL + col, a2 = j * NCOL + col;
            float a = sr[a1]; sr[a1] = sr[a2]; sr[a2] = a;
            float b = si[a1]; si[a1] = si[a2]; si[a2] = b;
        }
    }
    __syncthreads();

    for (int s = 1; s <= LOG2N; ++s) {
        int half = 1 << (s - 1);
        int m = half << 1;
        for (int b = tg; b < 256; b += 32) {
            int j = b & (half - 1);
            int grp = b >> (s - 1);
            int p1 = grp * m + j;
            int p2 = p1 + half;
            float ang = 6.283185307179586f * (float)j / (float)m;
            float sn, cs;
            __sincosf(ang, &sn, &cs);
            int a1 = p1 * NCOL + col, a2 = p2 * NCOL + col;
            float xr2 = sr[a2], xi2 = si[a2];
            float tr = cs * xr2 - sn * xi2;
            float ti = cs * xi2 + sn * xr2;
            float ur = sr[a1], ui = si[a1];
            sr[a2] = ur - tr; si[a2] = ui - ti;
            sr[a1] = ur + tr; si[a1] = ui + ti;
        }
        __syncthreads();
    }

    for (int e = t; e < N * NCOL; e += 256) {
        int row = e >> 3, col2 = e & 7;
        base[(size_t)row * N + col2] = make_float2(sr[e], si[e]);
    }
}

// ============ combine: out = (-1)^(ny+nx) * sum_c conj(csm)*img ============
__global__ __launch_bounds__(256) void combine_kernel(const float* __restrict__ csr,
                                                      const float* __restrict__ csi,
                                                      const float2* __restrict__ grid,
                                                      float* __restrict__ out) {
    int pix = blockIdx.x * 256 + threadIdx.x;
    int ny = pix >> LOG2N, nx = pix & (N - 1);
    float ar = 0.f, ai = 0.f;
#pragma unroll
    for (int c = 0; c < C; ++c) {
        float2 uv = grid[(size_t)c * NN + pix];
        float a = csr[c * NN + pix];
        float b = csi[c * NN + pix];
        ar += a * uv.x + b * uv.y;
        ai += a * uv.y - b * uv.x;
    }
    float s = ((ny + nx) & 1) ? -1.f : 1.f;      // fftshift folded into output sign
    out[pix] = s * ar;
    out[NN + pix] = s * ai;
}

extern "C" void kernel_launch(void* const* d_in, const int* in_sizes, int n_in,
                              void* d_out, int out_size, void* d_ws, size_t ws_size,
                              hipStream_t stream) {
    const float* x_real   = (const float*)d_in[0];
    const float* x_imag   = (const float*)d_in[1];
    const float* csm_real = (const float*)d_in[2];
    const float* csm_imag = (const float*)d_in[3];
    const float2* traj    = (const float2*)d_in[4];
    const float* dcf      = (const float*)d_in[5];
    float* out = (float*)d_out;

    char* ws = (char*)d_ws;
    size_t o = 0;
    float* grid  = (float*)(ws + o); o += (size_t)C * NN * 2 * sizeof(float);  // 32 MB
    int*   cell  = (int*)(ws + o);   o += (size_t)K * sizeof(int);             // 1 MB
    float* sdcf  = (float*)(ws + o); o += (size_t)K * sizeof(float);           // 1 MB
    int*   count = (int*)(ws + o);   o += (size_t)NN * sizeof(int);            // 1 MB
    int*   offs  = (int*)(ws + o);   o += ((size_t)NN + 4) * sizeof(int);      // 1 MB (+pad)
    int*   cursor= (int*)(ws + o);   o += (size_t)NN * sizeof(int);            // 1 MB
    long long* pw = (long long*)(ws + o); o += (size_t)K * sizeof(long long);  // 2 MB
    int*   bsum  = (int*)(ws + o);   o += 256 * sizeof(int);
    int*   boffs = (int*)(ws + o);   o += 256 * sizeof(int);

    (void)hipMemsetAsync(count, 0, (size_t)NN * sizeof(int), stream);

    prep_hist_kernel<<<K / 256, 256, 0, stream>>>(traj, dcf, cell, sdcf, count);
    scan_reduce_kernel<<<256, 256, 0, stream>>>(count, bsum);
    scan_top_kernel<<<1, 256, 0, stream>>>(bsum, boffs, offs);
    scan_final_kernel<<<256, 256, 0, stream>>>(count, boffs, offs, cursor);
    place_kernel<<<K / 256, 256, 0, stream>>>(cell, sdcf, cursor, pw);
    build_rowfft_kernel<<<N * 8, 256, 0, stream>>>(offs, pw, x_real, x_imag, (float2*)grid);
    colfft_kernel<<<C * (N / NCOL), 256, 0, stream>>>((float2*)grid);
    combine_kernel<<<NN / 256, 256, 0, stream>>>(csm_real, csm_imag, (float2*)grid, out);
}

// Round 7
// 245.872 us; speedup vs baseline: 2.3492x; 1.0199x over previous
//
#include <hip/hip_runtime.h>
#include <math.h>

#define N 512
#define NN (N * N)
#define C 16
#define K 262144
#define LOG2N 9
#define NCOL 8

// ============ phase 1: bin points by cell (counting sort, no fp atomics) ============

// prep + histogram fused: cell index, sign-folded dcf, count per cell
__global__ __launch_bounds__(256) void prep_hist_kernel(const float2* __restrict__ traj,
                                                        const float* __restrict__ dcf,
                                                        int* __restrict__ cell,
                                                        float* __restrict__ sdcf,
                                                        int* __restrict__ count) {
    int k = blockIdx.x * 256 + threadIdx.x;
    float2 t = traj[k];
    // jnp.round is half-to-even; __float2int_rn matches.
    int iy = __float2int_rn((t.x + 0.5f) * (float)N) & (N - 1);
    int ix = __float2int_rn((t.y + 0.5f) * (float)N) & (N - 1);
    int cl = iy * N + ix;
    cell[k] = cl;
    float s = ((iy + ix) & 1) ? -1.0f : 1.0f;   // ifftshift folded into input sign
    sdcf[k] = dcf[k] * s;
    atomicAdd(&count[cl], 1);                    // avg 1 pt/cell -> low contention
}

// per-block reduce: 256 blocks x 1024 ints -> bsum[256]
__global__ __launch_bounds__(256) void scan_reduce_kernel(const int* __restrict__ count,
                                                          int* __restrict__ bsum) {
    __shared__ int sd[256];
    int t = threadIdx.x;
    const int4* c4 = (const int4*)count;
    int4 v = c4[blockIdx.x * 256 + t];
    sd[t] = v.x + v.y + v.z + v.w;
    __syncthreads();
    for (int d = 128; d > 0; d >>= 1) {
        if (t < d) sd[t] += sd[t + d];
        __syncthreads();
    }
    if (t == 0) bsum[blockIdx.x] = sd[0];
}

// single block: exclusive scan of bsum[256] -> boffs[256]; also offs[NN] = K
__global__ __launch_bounds__(256) void scan_top_kernel(const int* __restrict__ bsum,
                                                       int* __restrict__ boffs,
                                                       int* __restrict__ offs) {
    __shared__ int sd[256];
    int t = threadIdx.x;
    int v = bsum[t];
    sd[t] = v;
    __syncthreads();
    for (int d = 1; d < 256; d <<= 1) {
        int tmp = (t >= d) ? sd[t - d] : 0;
        __syncthreads();
        sd[t] += tmp;
        __syncthreads();
    }
    boffs[t] = sd[t] - v;   // exclusive
    if (t == 0) offs[NN] = K;
}

// per-block exclusive scan: offs[i] = global exclusive prefix; cursor = copy of offs
__global__ __launch_bounds__(256) void scan_final_kernel(const int* __restrict__ count,
                                                         const int* __restrict__ boffs,
                                                         int* __restrict__ offs,
                                                         int* __restrict__ cursor) {
    __shared__ int sd[256];
    int t = threadIdx.x;
    int base_idx = blockIdx.x * 256 + t;
    const int4* c4 = (const int4*)count;
    int4 v = c4[base_idx];
    int s = v.x + v.y + v.z + v.w;
    sd[t] = s;
    __syncthreads();
    for (int d = 1; d < 256; d <<= 1) {
        int tmp = (t >= d) ? sd[t - d] : 0;
        __syncthreads();
        sd[t] += tmp;
        __syncthreads();
    }
    int base = boffs[blockIdx.x] + sd[t] - s;    // global exclusive prefix for this thread's 4
    int4 o;
    o.x = base;
    o.y = base + v.x;
    o.z = base + v.x + v.y;
    o.w = base + v.x + v.y + v.z;
    ((int4*)offs)[base_idx] = o;
    ((int4*)cursor)[base_idx] = o;
}

// place: each point claims a unique slot; pack {k:18 | col:9 | w:32} into one 8B store
__global__ __launch_bounds__(256) void place_kernel(const int* __restrict__ cell,
                                                    const float* __restrict__ sdcf,
                                                    int* __restrict__ cursor,
                                                    long long* __restrict__ pw) {
    int k = blockIdx.x * 256 + threadIdx.x;
    int cl = cell[k];
    float w = sdcf[k];
    int p = atomicAdd(&cursor[cl], 1);
    unsigned int lo = (unsigned int)k | ((unsigned int)(cl & (N - 1)) << 18);
    unsigned long long packed = lo |
                                ((unsigned long long)(unsigned int)__float_as_int(w) << 32);
    pw[p] = (long long)packed;
}

// ============ fused grid-build + row FFT ============
// block = (row r, channel-group cg). blockIdx = r*8+cg -> XCD = cg (round-robin),
// so each XCD's L2 holds exactly its 2 channels' x arrays (4 MB).
// Point-parallel gather: every lane owns an independent point (coalesced pw
// loads, 4 independent x-gather streams/lane -> high MLP), scattering into LDS
// with ds_add_f32 atomics at the BIT-REVERSED column — this folds the FFT
// bit-reversal permutation into the scatter (random cols -> ~2-way LDS
// conflicts, free) and kills the 16-way-conflict swap loop.
__global__ __launch_bounds__(256) void build_rowfft_kernel(const int* __restrict__ offs,
                                                           const long long* __restrict__ pw,
                                                           const float* __restrict__ xr,
                                                           const float* __restrict__ xi,
                                                           float2* __restrict__ grid) {
    __shared__ float sr0[N], si0[N], sr1[N], si1[N];
    int b = blockIdx.x;
    int cg = b & 7;
    int r = b >> 3;
    int c0 = cg * 2;
    int t = threadIdx.x;
    const float* xr0 = xr + (size_t)c0 * K;
    const float* xi0 = xi + (size_t)c0 * K;
    const float* xr1 = xr + (size_t)(c0 + 1) * K;
    const float* xi1 = xi + (size_t)(c0 + 1) * K;

    for (int i = t; i < N; i += 256) { sr0[i] = 0.f; si0[i] = 0.f; sr1[i] = 0.f; si1[i] = 0.f; }
    int start = offs[r * N];
    int end   = offs[r * N + N];   // r=511 uses offs[NN]=K
    __syncthreads();

    // point-parallel scatter: ~512 points per row, 2 iterations of 256 lanes
    for (int p = start + t; p < end; p += 256) {
        unsigned long long kw = (unsigned long long)__builtin_nontemporal_load(&pw[p]);
        int k   = (int)(kw & 0x3FFFFu);
        int col = (int)((kw >> 18) & 0x1FFu);
        float w = __int_as_float((int)(kw >> 32));
        int bc = (int)(__brev((unsigned)col) >> (32 - LOG2N));   // bit-reversed col
        float vr0 = xr0[k] * w;
        float vi0 = xi0[k] * w;
        float vr1 = xr1[k] * w;
        float vi1 = xi1[k] * w;
        atomicAdd(&sr0[bc], vr0);
        atomicAdd(&si0[bc], vi0);
        atomicAdd(&sr1[bc], vr1);
        atomicAdd(&si1[bc], vi1);
    }
    __syncthreads();

    // 9 radix-2 DIT stages, +i exponent; input already bit-reversed, output natural
    for (int s = 1; s <= LOG2N; ++s) {
        int half = 1 << (s - 1);
        int m = half << 1;
        int j = t & (half - 1);
        int grp = t >> (s - 1);
        int p1 = grp * m + j;
        int p2 = p1 + half;
        float ang = 6.283185307179586f * (float)j / (float)m;
        float sn, cs;
        __sincosf(ang, &sn, &cs);
        float x2, y2, tr, ti, ur, ui;
        x2 = sr0[p2]; y2 = si0[p2];
        tr = cs * x2 - sn * y2; ti = cs * y2 + sn * x2;
        ur = sr0[p1]; ui = si0[p1];
        sr0[p2] = ur - tr; si0[p2] = ui - ti;
        sr0[p1] = ur + tr; si0[p1] = ui + ti;
        x2 = sr1[p2]; y2 = si1[p2];
        tr = cs * x2 - sn * y2; ti = cs * y2 + sn * x2;
        ur = sr1[p1]; ui = si1[p1];
        sr1[p2] = ur - tr; si1[p2] = ui - ti;
        sr1[p1] = ur + tr; si1[p1] = ui + ti;
        __syncthreads();
    }

    float2* g0 = grid + (size_t)c0 * NN + (size_t)r * N;
    float2* g1 = grid + (size_t)(c0 + 1) * NN + (size_t)r * N;
    for (int i = t; i < N; i += 256) {
        g0[i] = make_float2(sr0[i], si0[i]);
        g1[i] = make_float2(sr1[i], si1[i]);
    }
}

// ============ column FFT: NCOL columns per block through LDS ============
__global__ __launch_bounds__(256) void colfft_kernel(float2* __restrict__ grid) {
    __shared__ float sr[N * NCOL];
    __shared__ float si[N * NCOL];
    int blk = blockIdx.x;                        // c * (N/NCOL) + cg
    int c = blk >> 6;
    int cg = blk & 63;
    float2* base = grid + (size_t)c * NN + cg * NCOL;
    int t = threadIdx.x;

    for (int e = t; e < N * NCOL; e += 256) {
        int row = e >> 3, col = e & 7;
        float2 v = base[(size_t)row * N + col];
        sr[e] = v.x; si[e] = v.y;
    }
    __syncthreads();

    int col = t & 7;
    int tg = t >> 3;
    for (int i = tg; i < N; i += 32) {
        int j = __brev((unsigned)i) >> (32 - LOG2N);
        if (j > i) {
            int a1 = i * NCOL + col, a2 = j * NCOL + col;
            float a = sr[a1]; sr[a1] = sr[a2]; sr[a2] = a;
            float b = si[a1]; si[a1] = si[a2]; si[a2] = b;
        }
    }
    __syncthreads();

    for (int s = 1; s <= LOG2N; ++s) {
        int half = 1 << (s - 1);
        int m = half << 1;
        for (int b = tg; b < 256; b += 32) {
            int j = b & (half - 1);
            int grp = b >> (s - 1);
            int p1 = grp * m + j;
            int p2 = p1 + half;
            float ang = 6.283185307179586f * (float)j / (float)m;
            float sn, cs;
            __sincosf(ang, &sn, &cs);
            int a1 = p1 * NCOL + col, a2 = p2 * NCOL + col;
            float xr2 = sr[a2], xi2 = si[a2];
            float tr = cs * xr2 - sn * xi2;
            float ti = cs * xi2 + sn * xr2;
            float ur = sr[a1], ui = si[a1];
            sr[a2] = ur - tr; si[a2] = ui - ti;
            sr[a1] = ur + tr; si[a1] = ui + ti;
        }
        __syncthreads();
    }

    for (int e = t; e < N * NCOL; e += 256) {
        int row = e >> 3, col2 = e & 7;
        base[(size_t)row * N + col2] = make_float2(sr[e], si[e]);
    }
}

// ============ combine: out = (-1)^(ny+nx) * sum_c conj(csm)*img ============
__global__ __launch_bounds__(256) void combine_kernel(const float* __restrict__ csr,
                                                      const float* __restrict__ csi,
                                                      const float2* __restrict__ grid,
                                                      float* __restrict__ out) {
    int pix = blockIdx.x * 256 + threadIdx.x;
    int ny = pix >> LOG2N, nx = pix & (N - 1);
    float ar = 0.f, ai = 0.f;
#pragma unroll
    for (int c = 0; c < C; ++c) {
        float2 uv = grid[(size_t)c * NN + pix];
        float a = csr[c * NN + pix];
        float b = csi[c * NN + pix];
        ar += a * uv.x + b * uv.y;
        ai += a * uv.y - b * uv.x;
    }
    float s = ((ny + nx) & 1) ? -1.f : 1.f;      // fftshift folded into output sign
    out[pix] = s * ar;
    out[NN + pix] = s * ai;
}

extern "C" void kernel_launch(void* const* d_in, const int* in_sizes, int n_in,
                              void* d_out, int out_size, void* d_ws, size_t ws_size,
                              hipStream_t stream) {
    const float* x_real   = (const float*)d_in[0];
    const float* x_imag   = (const float*)d_in[1];
    const float* csm_real = (const float*)d_in[2];
    const float* csm_imag = (const float*)d_in[3];
    const float2* traj    = (const float2*)d_in[4];
    const float* dcf      = (const float*)d_in[5];
    float* out = (float*)d_out;

    char* ws = (char*)d_ws;
    size_t o = 0;
    float* grid  = (float*)(ws + o); o += (size_t)C * NN * 2 * sizeof(float);  // 32 MB
    int*   cell  = (int*)(ws + o);   o += (size_t)K * sizeof(int);             // 1 MB
    float* sdcf  = (float*)(ws + o); o += (size_t)K * sizeof(float);           // 1 MB
    int*   count = (int*)(ws + o);   o += (size_t)NN * sizeof(int);            // 1 MB
    int*   offs  = (int*)(ws + o);   o += ((size_t)NN + 4) * sizeof(int);      // 1 MB (+pad)
    int*   cursor= (int*)(ws + o);   o += (size_t)NN * sizeof(int);            // 1 MB
    long long* pw = (long long*)(ws + o); o += (size_t)K * sizeof(long long);  // 2 MB
    int*   bsum  = (int*)(ws + o);   o += 256 * sizeof(int);
    int*   boffs = (int*)(ws + o);   o += 256 * sizeof(int);

    (void)hipMemsetAsync(count, 0, (size_t)NN * sizeof(int), stream);

    prep_hist_kernel<<<K / 256, 256, 0, stream>>>(traj, dcf, cell, sdcf, count);
    scan_reduce_kernel<<<256, 256, 0, stream>>>(count, bsum);
    scan_top_kernel<<<1, 256, 0, stream>>>(bsum, boffs, offs);
    scan_final_kernel<<<256, 256, 0, stream>>>(count, boffs, offs, cursor);
    place_kernel<<<K / 256, 256, 0, stream>>>(cell, sdcf, cursor, pw);
    build_rowfft_kernel<<<N * 8, 256, 0, stream>>>(offs, pw, x_real, x_imag, (float2*)grid);
    colfft_kernel<<<C * (N / NCOL), 256, 0, stream>>>((float2*)grid);
    combine_kernel<<<NN / 256, 256, 0, stream>>>(csm_real, csm_imag, (float2*)grid, out);
}